// Round 10
// baseline (361.579 us; speedup 1.0000x reference)
//
#include <hip/hip_runtime.h>
#include <math.h>

// Problem constants (match reference)
#define N_NODES 50000
#define N_EDGES 800000
#define DFEAT   128
#define MAXNORM (1.0f - 4e-3f)   // (1 - BALL_EPS)/sqrt(c), c=1
#define CAP     64               // padded adjacency slots per row (deg ~ Poisson(16), max ~45)
#define OVF_CAP 8192
#define NB      512              // buckets
#define NPB     98               // nodes per bucket (512*98 = 50176 >= 50000)
#define BKT_CAP 2048             // edges per bucket (mean ~1568, 6-sigma safe; excess -> ovf)
#define SENT    N_NODES          // sentinel node id (fits ushort, xb row is zeros)

// ==================== tier 1: binned build + pre-scaled bf16 gather ====================

__global__ void k_zero(int* __restrict__ bcnt, int* __restrict__ ovf_cnt) {
    int i = blockIdx.x * blockDim.x + threadIdx.x;
    if (i < NB) bcnt[i] = 0;
    if (i == NB) *ovf_cnt = 0;
}

// Phase 1: bin edges by destination-node range. Appends fill bucket tail lines
// densely (L2-hot), replacing r9's 51 MB of random 64B-line dirtying with ~3 MB.
__global__ void k_bin(const int* __restrict__ row, const int* __restrict__ col,
                      int* __restrict__ bcnt, unsigned int* __restrict__ bucket,
                      int* __restrict__ ovf, int* __restrict__ ovf_cnt, int e) {
    int i = blockIdx.x * blockDim.x + threadIdx.x;
    if (i >= e) return;
    int r = row[i], c = col[i];
    if (r == c) return;
    int b = r / NPB;
    int pos = atomicAdd(&bcnt[b], 1);
    if (pos < BKT_CAP) bucket[b * BKT_CAP + pos] = ((unsigned int)r << 16) | (unsigned int)c;
    else {
        int o = atomicAdd(ovf_cnt, 1);
        if (o < OVF_CAP) { ovf[2 * o] = r; ovf[2 * o + 1] = c; }
    }
}

__device__ __forceinline__ unsigned int pack_bf16(float lo_f, float hi_f) {
    unsigned int lo = __float_as_uint(lo_f);
    unsigned int hi = __float_as_uint(hi_f);
    lo = (lo + 0x7FFFu + ((lo >> 16) & 1u)) >> 16;   // RNE to bf16
    hi = (hi + 0x7FFFu + ((hi >> 16) & 1u)) >> 16;
    return lo | (hi << 16);
}

// Phase 2: one block per bucket. Build deg + sentinel-padded ushort adj rows in
// LDS (LDS atomics only), write out coalesced. Fused: also stages this bucket's
// x rows as bf16 pre-scaled by rsqrt(deg+1) (replaces the old k_prep).
__global__ __launch_bounds__(256) void k_bucket(const float* __restrict__ x,
                                                const unsigned int* __restrict__ bucket,
                                                const int* __restrict__ bcnt,
                                                int* __restrict__ deg,
                                                unsigned short* __restrict__ adj16,
                                                unsigned int* __restrict__ xb,
                                                int* __restrict__ ovf, int* __restrict__ ovf_cnt) {
    __shared__ int ldeg[NPB];
    __shared__ __align__(16) unsigned short ladj[NPB * CAP];
    unsigned int* ladj32 = (unsigned int*)ladj;

    int b = blockIdx.x;
    int t = threadIdx.x;
    int nbase = b * NPB;

    for (int j = t; j < NPB; j += 256) ldeg[j] = 0;
    for (int j = t; j < NPB * CAP / 2; j += 256) ladj32[j] = (((unsigned)SENT) << 16) | (unsigned)SENT;
    __syncthreads();

    int cnt = bcnt[b];
    if (cnt > BKT_CAP) cnt = BKT_CAP;
    for (int j = t; j < cnt; j += 256) {
        unsigned int e = bucket[b * BKT_CAP + j];
        int r = (int)(e >> 16), c = (int)(e & 0xFFFFu);
        int lr = r - nbase;
        int pos = atomicAdd(&ldeg[lr], 1);
        if (pos < CAP) ladj[lr * CAP + pos] = (unsigned short)c;
        else {
            int o = atomicAdd(ovf_cnt, 1);
            if (o < OVF_CAP) { ovf[2 * o] = r; ovf[2 * o + 1] = c; }
        }
    }
    __syncthreads();

    int nclip = N_NODES - nbase;
    if (nclip > NPB) nclip = NPB;
    if (nclip > 0) {
        if (t < nclip) deg[nbase + t] = ldeg[t];
        // adj writeout: nclip rows x 32 uints, fully coalesced
        unsigned int* gadj = (unsigned int*)(adj16 + (size_t)nbase * CAP);
        int nw = nclip * (CAP / 2);
        for (int j = t; j < nw; j += 256) gadj[j] = ladj32[j];
        // xb writeout: nclip rows x 32 float4 -> uint2 (pre-scaled bf16)
        const float4* gx = (const float4*)(x + (size_t)nbase * DFEAT);
        uint2* gxb = (uint2*)xb;
        int nf4 = nclip * 32;
        for (int j = t; j < nf4; j += 256) {
            int node = j >> 5;
            float dis = rsqrtf((float)(ldeg[node] + 1));
            float4 v = gx[j];
            uint2 o;
            o.x = pack_bf16(v.x * dis, v.y * dis);
            o.y = pack_bf16(v.z * dis, v.w * dis);
            gxb[(size_t)(nbase + node) * 32 + (j & 31)] = o;
        }
    }
    if (b == NB - 1) {   // sentinel row (node N_NODES): zeros
        for (int j = t; j < DFEAT / 2; j += 256) xb[(size_t)N_NODES * (DFEAT / 2) + j] = 0u;
    }
}

__device__ __forceinline__ float bf_lo(unsigned int w) { return __uint_as_float(w << 16); }
__device__ __forceinline__ float bf_hi(unsigned int w) { return __uint_as_float(w & 0xFFFF0000u); }

// One wave per destination row (r9-proven structure). adj rows are sentinel-
// padded ushort; xb rows pre-scaled by dis[src]; sentinel row is zeros.
__global__ __launch_bounds__(256) void k_gather_bf(const unsigned int* __restrict__ xb,
                                                   const unsigned short* __restrict__ adj16,
                                                   const int* __restrict__ deg,
                                                   const int* __restrict__ ovf,
                                                   const int* __restrict__ ovf_cnt,
                                                   float* __restrict__ out, int n) {
    int lane = threadIdx.x & 63;
    int half = lane >> 5;
    int fl   = lane & 31;
    int rowi = blockIdx.x * 4 + (threadIdx.x >> 6);
    if (rowi >= n) return;

    int cnt    = deg[rowi];
    int capcnt = cnt < CAP ? cnt : CAP;
    int capR   = (capcnt + 7) & ~7;                  // trip count, 8 neighbors/iter

    int a = (int)adj16[rowi * CAP + lane];           // rows pre-padded with sentinel

    const unsigned int* __restrict__ xw = xb + 2 * fl;   // lane's word pair base

    float acc0 = 0.f, acc1 = 0.f, acc2 = 0.f, acc3 = 0.f;
    for (int nb = 0; nb < capR; nb += 8) {
        int c0 = __shfl(a, nb + 0 + half);
        int c1 = __shfl(a, nb + 2 + half);
        int c2 = __shfl(a, nb + 4 + half);
        int c3 = __shfl(a, nb + 6 + half);
        uint2 v0 = *(const uint2*)(xw + c0 * (DFEAT / 2));
        uint2 v1 = *(const uint2*)(xw + c1 * (DFEAT / 2));
        uint2 v2 = *(const uint2*)(xw + c2 * (DFEAT / 2));
        uint2 v3 = *(const uint2*)(xw + c3 * (DFEAT / 2));
        acc0 += bf_lo(v0.x); acc1 += bf_hi(v0.x); acc2 += bf_lo(v0.y); acc3 += bf_hi(v0.y);
        acc0 += bf_lo(v1.x); acc1 += bf_hi(v1.x); acc2 += bf_lo(v1.y); acc3 += bf_hi(v1.y);
        acc0 += bf_lo(v2.x); acc1 += bf_hi(v2.x); acc2 += bf_lo(v2.y); acc3 += bf_hi(v2.y);
        acc0 += bf_lo(v3.x); acc1 += bf_hi(v3.x); acc2 += bf_lo(v3.y); acc3 += bf_hi(v3.y);
    }

    // overflow edges (statistically never non-empty); lanes 0-31 only, pre-combine
    int novf = *ovf_cnt;
    if (novf > 0 && half == 0) {
        for (int k = 0; k < novf; ++k) {
            if (ovf[2 * k] == rowi) {
                uint2 v = *(const uint2*)(xw + ovf[2 * k + 1] * (DFEAT / 2));
                acc0 += bf_lo(v.x); acc1 += bf_hi(v.x);
                acc2 += bf_lo(v.y); acc3 += bf_hi(v.y);
            }
        }
    }

    // combine halves (afterwards both halves hold identical full sums)
    acc0 += __shfl_xor(acc0, 32);
    acc1 += __shfl_xor(acc1, 32);
    acc2 += __shfl_xor(acc2, 32);
    acc3 += __shfl_xor(acc3, 32);

    // self term: xb[rowi] pre-scaled by dis[rowi]
    uint2 sv = *(const uint2*)(xw + rowi * (DFEAT / 2));
    acc0 += bf_lo(sv.x); acc1 += bf_hi(sv.x);
    acc2 += bf_lo(sv.y); acc3 += bf_hi(sv.y);

    float di = rsqrtf((float)(cnt + 1));             // dis[row]
    acc0 *= di; acc1 *= di; acc2 *= di; acc3 *= di;

    // norm^2: reduce within each 32-half (halves identical)
    float nsq = acc0 * acc0 + acc1 * acc1 + acc2 * acc2 + acc3 * acc3;
    #pragma unroll
    for (int off = 16; off > 0; off >>= 1) nsq += __shfl_xor(nsq, off);

    float un = fmaxf(sqrtf(nsq), 1e-15f);
    float th = tanhf(un);
    float scale = th / un;                           // expmap0
    if (th > MAXNORM) scale *= MAXNORM / th;         // proj clamp (||p|| == tanh(un))

    if (half == 0) {
        float4 o = make_float4(acc0 * scale, acc1 * scale, acc2 * scale, acc3 * scale);
        *(float4*)(out + (size_t)rowi * DFEAT + 4 * fl) = o;
    }
}

// ==================== fallback: CSR path (proven round-2) ====================

#define SCAN_BLK 256
#define NUM_SCAN_BLOCKS ((N_NODES + SCAN_BLK - 1) / SCAN_BLK)

__global__ void k_init_deg(int* __restrict__ deg, int n) {
    int i = blockIdx.x * blockDim.x + threadIdx.x;
    if (i < n) deg[i] = 1;
}

__global__ void k_hist(const int* __restrict__ row, const int* __restrict__ col,
                       int* __restrict__ deg, int e) {
    int i = blockIdx.x * blockDim.x + threadIdx.x;
    if (i < e) {
        int r = row[i], c = col[i];
        if (r != c) atomicAdd(&deg[r], 1);
    }
}

__global__ __launch_bounds__(SCAN_BLK) void k_block_sums(const int* __restrict__ deg,
                                                         int* __restrict__ blockSums, int n) {
    __shared__ int s[SCAN_BLK];
    int t = threadIdx.x;
    int i = blockIdx.x * SCAN_BLK + t;
    s[t] = (i < n) ? (deg[i] - 1) : 0;
    __syncthreads();
    for (int off = SCAN_BLK / 2; off > 0; off >>= 1) {
        if (t < off) s[t] += s[t + off];
        __syncthreads();
    }
    if (t == 0) blockSums[blockIdx.x] = s[0];
}

__global__ __launch_bounds__(SCAN_BLK) void k_scan_blocks(const int* __restrict__ blockSums,
                                                          int* __restrict__ blockBase) {
    __shared__ int s[SCAN_BLK];
    int t = threadIdx.x;
    s[t] = (t < NUM_SCAN_BLOCKS) ? blockSums[t] : 0;
    __syncthreads();
    for (int off = 1; off < SCAN_BLK; off <<= 1) {
        int v = (t >= off) ? s[t - off] : 0;
        __syncthreads();
        s[t] += v;
        __syncthreads();
    }
    if (t < NUM_SCAN_BLOCKS) blockBase[t] = (t == 0) ? 0 : s[t - 1];
}

__global__ __launch_bounds__(SCAN_BLK) void k_block_scan(const int* __restrict__ deg,
                                                         const int* __restrict__ blockBase,
                                                         int* __restrict__ offs,
                                                         int* __restrict__ cursor, int n) {
    __shared__ int s[SCAN_BLK];
    int t = threadIdx.x;
    int i = blockIdx.x * SCAN_BLK + t;
    int cnt = (i < n) ? (deg[i] - 1) : 0;
    s[t] = cnt;
    __syncthreads();
    for (int off = 1; off < SCAN_BLK; off <<= 1) {
        int v = (t >= off) ? s[t - off] : 0;
        __syncthreads();
        s[t] += v;
        __syncthreads();
    }
    if (i < n) {
        int excl = s[t] - cnt + blockBase[blockIdx.x];
        offs[i]   = excl;
        cursor[i] = excl;
    }
}

__global__ void k_scatter(const int* __restrict__ row, const int* __restrict__ col,
                          int* __restrict__ cursor, int* __restrict__ adj, int e) {
    int i = blockIdx.x * blockDim.x + threadIdx.x;
    if (i < e) {
        int r = row[i], c = col[i];
        if (r != c) {
            int pos = atomicAdd(&cursor[r], 1);
            adj[pos] = c;
        }
    }
}

__global__ __launch_bounds__(256) void k_gather_csr(const float* __restrict__ x,
                                                    const int* __restrict__ adj,
                                                    const int* __restrict__ offs,
                                                    const int* __restrict__ deg,
                                                    float* __restrict__ out, int n) {
    int lane = threadIdx.x & 63;
    int rowi = blockIdx.x * 4 + (threadIdx.x >> 6);
    if (rowi >= n) return;

    const float2* __restrict__ x2 = (const float2*)x;
    int beg = offs[rowi];
    int cnt = deg[rowi] - 1;

    float2 acc = make_float2(0.0f, 0.0f);
    for (int base = 0; base < cnt; base += 64) {
        int m = cnt - base; if (m > 64) m = 64;
        int a = 0;
        if (lane < m) a = adj[beg + base + lane];
        for (int nb = 0; nb < m; ++nb) {
            int c = __shfl(a, nb);
            float w = rsqrtf((float)deg[c]);
            float2 v = x2[c * (DFEAT / 2) + lane];
            acc.x += w * v.x;
            acc.y += w * v.y;
        }
    }
    float di = rsqrtf((float)deg[rowi]);
    float2 self = x2[rowi * (DFEAT / 2) + lane];
    acc.x = di * (acc.x + di * self.x);
    acc.y = di * (acc.y + di * self.y);

    float nsq = acc.x * acc.x + acc.y * acc.y;
    #pragma unroll
    for (int off = 32; off > 0; off >>= 1) nsq += __shfl_xor(nsq, off);

    float un = fmaxf(sqrtf(nsq), 1e-15f);
    float th = tanhf(un);
    float scale = th / un;
    if (th > MAXNORM) scale *= MAXNORM / th;

    float2 o = make_float2(acc.x * scale, acc.y * scale);
    ((float2*)out)[rowi * (DFEAT / 2) + lane] = o;
}

// ==================== launcher ====================

extern "C" void kernel_launch(void* const* d_in, const int* in_sizes, int n_in,
                              void* d_out, int out_size, void* d_ws, size_t ws_size,
                              hipStream_t stream) {
    const float* x          = (const float*)d_in[0];
    const int*   edge_index = (const int*)d_in[1];
    const int*   row = edge_index;            // [E]
    const int*   col = edge_index + N_EDGES;  // [E]
    float* out = (float*)d_out;
    char*  ws  = (char*)d_ws;

    size_t sz_xb     = sizeof(unsigned short) * (size_t)(N_NODES + 1) * DFEAT;  // 12.80 MB (16B-mult)
    size_t sz_bucket = sizeof(unsigned int) * (size_t)NB * BKT_CAP;             //  4.19 MB
    size_t sz_adj16  = sizeof(unsigned short) * (size_t)N_NODES * CAP;          //  6.40 MB
    size_t sz_deg    = sizeof(int) * (size_t)N_NODES;
    size_t sz_bcnt   = sizeof(int) * (size_t)NB;
    size_t need = sz_xb + sz_bucket + sz_adj16 + sz_deg + sz_bcnt
                + sizeof(int) * (1 + 2 * (size_t)OVF_CAP);                      // ~23.7 MB

    dim3 blk(256);
    if (ws_size >= need) {
        size_t off = 0;
        unsigned int*   xb     = (unsigned int*)(ws + off);   off += sz_xb;
        unsigned int*   bucket = (unsigned int*)(ws + off);   off += sz_bucket;
        unsigned short* adj16  = (unsigned short*)(ws + off); off += sz_adj16;
        int*            deg    = (int*)(ws + off);            off += sz_deg;
        int*            bcnt   = (int*)(ws + off);            off += sz_bcnt;
        int*            ovf_cnt= (int*)(ws + off);            off += sizeof(int);
        int*            ovf    = (int*)(ws + off);

        k_zero<<<dim3((NB + 1 + 255) / 256), blk, 0, stream>>>(bcnt, ovf_cnt);
        k_bin<<<dim3((N_EDGES + 255) / 256), blk, 0, stream>>>(row, col, bcnt, bucket, ovf, ovf_cnt, N_EDGES);
        k_bucket<<<dim3(NB), blk, 0, stream>>>(x, bucket, bcnt, deg, adj16, xb, ovf, ovf_cnt);
        k_gather_bf<<<dim3((N_NODES + 3) / 4), blk, 0, stream>>>(xb, adj16, deg, ovf, ovf_cnt, out, N_NODES);
    } else {
        size_t off = 0;
        int* deg       = (int*)(ws + off); off += sizeof(int) * (size_t)N_NODES;
        int* offs      = (int*)(ws + off); off += sizeof(int) * (size_t)N_NODES;
        int* cursor    = (int*)(ws + off); off += sizeof(int) * (size_t)N_NODES;
        int* blockSums = (int*)(ws + off); off += sizeof(int) * (size_t)NUM_SCAN_BLOCKS;
        int* blockBase = (int*)(ws + off); off += sizeof(int) * (size_t)NUM_SCAN_BLOCKS;
        int* adj       = (int*)(ws + off);

        k_init_deg<<<dim3((N_NODES + 255) / 256), blk, 0, stream>>>(deg, N_NODES);
        k_hist<<<dim3((N_EDGES + 255) / 256), blk, 0, stream>>>(row, col, deg, N_EDGES);
        k_block_sums<<<dim3(NUM_SCAN_BLOCKS), dim3(SCAN_BLK), 0, stream>>>(deg, blockSums, N_NODES);
        k_scan_blocks<<<dim3(1), dim3(SCAN_BLK), 0, stream>>>(blockSums, blockBase);
        k_block_scan<<<dim3(NUM_SCAN_BLOCKS), dim3(SCAN_BLK), 0, stream>>>(deg, blockBase, offs, cursor, N_NODES);
        k_scatter<<<dim3((N_EDGES + 255) / 256), blk, 0, stream>>>(row, col, cursor, adj, N_EDGES);
        k_gather_csr<<<dim3((N_NODES + 3) / 4), blk, 0, stream>>>(x, adj, offs, deg, out, N_NODES);
    }
}

// Round 11
// 148.611 us; speedup vs baseline: 2.4331x; 2.4331x over previous
//
#include <hip/hip_runtime.h>
#include <math.h>

// Problem constants (match reference)
#define N_NODES 50000
#define N_EDGES 800000
#define DFEAT   128
#define MAXNORM (1.0f - 4e-3f)   // (1 - BALL_EPS)/sqrt(c), c=1
#define CAP     64               // padded adjacency slots per row (deg ~ Poisson(16), max ~45)
#define OVF_CAP 8192
#define NPART   8                // row partitions (~XCDs)
#define PSIZE   (N_NODES / NPART) // 6250 rows per partition
#define SENT    N_NODES          // sentinel node id (xb row is zeros)

// ==================== tier 1: partitioned build + pre-scaled bf16 gather ====================

__global__ void k_zero(int* __restrict__ deg, int* __restrict__ ovf_cnt, int n) {
    int i = blockIdx.x * blockDim.x + threadIdx.x;
    if (i < n) deg[i] = 0;
    if (i == 0) *ovf_cnt = 0;
}

// Row-partitioned build: blocks with (blockIdx&7)==p handle only rows in
// partition p (6250 rows). With the blockIdx%8 -> XCD round-robin heuristic,
// each partition's deg atomics + adj stores stay in ONE XCD's L2 (single-owner
// lines -> no cross-XCD writeback amplification; r9 showed 48 MB WRITE for
// 3.2 MB payload). All partitions scan all edges (8x coalesced reads, cheap).
// Correctness does NOT depend on the XCD mapping.
__global__ void k_build(const int* __restrict__ row, const int* __restrict__ col,
                        int* __restrict__ deg, unsigned short* __restrict__ adj16,
                        int* __restrict__ ovf, int* __restrict__ ovf_cnt, int e) {
    int p      = blockIdx.x & (NPART - 1);
    int vblock = blockIdx.x >> 3;
    int stride = (gridDim.x >> 3) * blockDim.x;
    int lo = p * PSIZE, hi = lo + PSIZE;
    for (int i = vblock * blockDim.x + threadIdx.x; i < e; i += stride) {
        int r = row[i], c = col[i];
        if (r < lo || r >= hi || r == c) continue;
        int pos = atomicAdd(&deg[r], 1);
        if (pos < CAP) adj16[r * CAP + pos] = (unsigned short)c;
        else {
            int o = atomicAdd(ovf_cnt, 1);
            if (o < OVF_CAP) { ovf[2 * o] = r; ovf[2 * o + 1] = c; }
        }
    }
}

// After build: xb[node] = bf16(x[node] * rsqrt(deg[node]+1)); row N_NODES = zeros.
// 16 threads per row (8 floats each).
__global__ __launch_bounds__(256) void k_prep(const float* __restrict__ x,
                                              const int* __restrict__ deg,
                                              unsigned int* __restrict__ xb,   // packed 2x bf16 per word
                                              int nthreads) {
    int t = blockIdx.x * blockDim.x + threadIdx.x;
    if (t >= nthreads) return;

    int node = t >> 4;            // 16 threads per row
    int part = t & 15;            // which 8-float chunk
    unsigned int w[4];
    if (node < N_NODES) {
        float dis = rsqrtf((float)(deg[node] + 1));
        const float4* x4 = (const float4*)(x + (size_t)node * DFEAT + part * 8);
        float4 a = x4[0];
        float4 b = x4[1];
        float fs[8] = {a.x, a.y, a.z, a.w, b.x, b.y, b.z, b.w};
        #pragma unroll
        for (int k = 0; k < 4; ++k) {
            unsigned int lo = __float_as_uint(fs[2 * k] * dis);
            unsigned int hi = __float_as_uint(fs[2 * k + 1] * dis);
            lo = (lo + 0x7FFFu + ((lo >> 16) & 1u)) >> 16;          // RNE to bf16
            hi = (hi + 0x7FFFu + ((hi >> 16) & 1u)) >> 16;
            w[k] = lo | (hi << 16);
        }
    } else {
        w[0] = w[1] = w[2] = w[3] = 0u;   // sentinel row: zeros
    }
    ((uint4*)xb)[t] = make_uint4(w[0], w[1], w[2], w[3]);
}

__device__ __forceinline__ float bf_lo(unsigned int w) { return __uint_as_float(w << 16); }
__device__ __forceinline__ float bf_hi(unsigned int w) { return __uint_as_float(w & 0xFFFF0000u); }

// One wave per destination row (r9-proven structure, ushort adj). xb rows
// pre-scaled by dis[src]; sentinel row is zeros; lanes >= capcnt masked to
// sentinel in-register. Each lane loads uint2 (4 bf16): one VMEM instruction
// per TWO neighbors, unrolled x4 (8 neighbors/iter).
__global__ __launch_bounds__(256) void k_gather_bf(const unsigned int* __restrict__ xb,
                                                   const unsigned short* __restrict__ adj16,
                                                   const int* __restrict__ deg,
                                                   const int* __restrict__ ovf,
                                                   const int* __restrict__ ovf_cnt,
                                                   float* __restrict__ out, int n) {
    int lane = threadIdx.x & 63;
    int half = lane >> 5;
    int fl   = lane & 31;
    int rowi = blockIdx.x * 4 + (threadIdx.x >> 6);
    if (rowi >= n) return;

    int cnt    = deg[rowi];
    int capcnt = cnt < CAP ? cnt : CAP;
    int capR   = (capcnt + 7) & ~7;                  // trip count, 8 neighbors/iter

    int a = SENT;
    if (lane < capcnt) a = (int)adj16[rowi * CAP + lane];  // coalesced 128B per row

    const unsigned int* __restrict__ xw = xb + 2 * fl;     // lane's word pair base

    float acc0 = 0.f, acc1 = 0.f, acc2 = 0.f, acc3 = 0.f;
    for (int nb = 0; nb < capR; nb += 8) {
        int c0 = __shfl(a, nb + 0 + half);
        int c1 = __shfl(a, nb + 2 + half);
        int c2 = __shfl(a, nb + 4 + half);
        int c3 = __shfl(a, nb + 6 + half);
        uint2 v0 = *(const uint2*)(xw + c0 * (DFEAT / 2));
        uint2 v1 = *(const uint2*)(xw + c1 * (DFEAT / 2));
        uint2 v2 = *(const uint2*)(xw + c2 * (DFEAT / 2));
        uint2 v3 = *(const uint2*)(xw + c3 * (DFEAT / 2));
        acc0 += bf_lo(v0.x); acc1 += bf_hi(v0.x); acc2 += bf_lo(v0.y); acc3 += bf_hi(v0.y);
        acc0 += bf_lo(v1.x); acc1 += bf_hi(v1.x); acc2 += bf_lo(v1.y); acc3 += bf_hi(v1.y);
        acc0 += bf_lo(v2.x); acc1 += bf_hi(v2.x); acc2 += bf_lo(v2.y); acc3 += bf_hi(v2.y);
        acc0 += bf_lo(v3.x); acc1 += bf_hi(v3.x); acc2 += bf_lo(v3.y); acc3 += bf_hi(v3.y);
    }

    // overflow edges (statistically never non-empty); lanes 0-31 only, pre-combine
    int novf = *ovf_cnt;
    if (novf > 0 && half == 0) {
        for (int k = 0; k < novf; ++k) {
            if (ovf[2 * k] == rowi) {
                uint2 v = *(const uint2*)(xw + ovf[2 * k + 1] * (DFEAT / 2));
                acc0 += bf_lo(v.x); acc1 += bf_hi(v.x);
                acc2 += bf_lo(v.y); acc3 += bf_hi(v.y);
            }
        }
    }

    // combine halves (afterwards both halves hold identical full sums)
    acc0 += __shfl_xor(acc0, 32);
    acc1 += __shfl_xor(acc1, 32);
    acc2 += __shfl_xor(acc2, 32);
    acc3 += __shfl_xor(acc3, 32);

    // self term: xb[rowi] pre-scaled by dis[rowi]
    uint2 sv = *(const uint2*)(xw + rowi * (DFEAT / 2));
    acc0 += bf_lo(sv.x); acc1 += bf_hi(sv.x);
    acc2 += bf_lo(sv.y); acc3 += bf_hi(sv.y);

    float di = rsqrtf((float)(cnt + 1));             // dis[row]
    acc0 *= di; acc1 *= di; acc2 *= di; acc3 *= di;

    // norm^2: reduce within each 32-half (halves identical)
    float nsq = acc0 * acc0 + acc1 * acc1 + acc2 * acc2 + acc3 * acc3;
    #pragma unroll
    for (int off = 16; off > 0; off >>= 1) nsq += __shfl_xor(nsq, off);

    float un = fmaxf(sqrtf(nsq), 1e-15f);
    float th = tanhf(un);
    float scale = th / un;                           // expmap0
    if (th > MAXNORM) scale *= MAXNORM / th;         // proj clamp (||p|| == tanh(un))

    if (half == 0) {
        float4 o = make_float4(acc0 * scale, acc1 * scale, acc2 * scale, acc3 * scale);
        *(float4*)(out + (size_t)rowi * DFEAT + 4 * fl) = o;
    }
}

// ==================== fallback: CSR path (proven round-2) ====================

#define SCAN_BLK 256
#define NUM_SCAN_BLOCKS ((N_NODES + SCAN_BLK - 1) / SCAN_BLK)

__global__ void k_init_deg(int* __restrict__ deg, int n) {
    int i = blockIdx.x * blockDim.x + threadIdx.x;
    if (i < n) deg[i] = 1;
}

__global__ void k_hist(const int* __restrict__ row, const int* __restrict__ col,
                       int* __restrict__ deg, int e) {
    int i = blockIdx.x * blockDim.x + threadIdx.x;
    if (i < e) {
        int r = row[i], c = col[i];
        if (r != c) atomicAdd(&deg[r], 1);
    }
}

__global__ __launch_bounds__(SCAN_BLK) void k_block_sums(const int* __restrict__ deg,
                                                         int* __restrict__ blockSums, int n) {
    __shared__ int s[SCAN_BLK];
    int t = threadIdx.x;
    int i = blockIdx.x * SCAN_BLK + t;
    s[t] = (i < n) ? (deg[i] - 1) : 0;
    __syncthreads();
    for (int off = SCAN_BLK / 2; off > 0; off >>= 1) {
        if (t < off) s[t] += s[t + off];
        __syncthreads();
    }
    if (t == 0) blockSums[blockIdx.x] = s[0];
}

__global__ __launch_bounds__(SCAN_BLK) void k_scan_blocks(const int* __restrict__ blockSums,
                                                          int* __restrict__ blockBase) {
    __shared__ int s[SCAN_BLK];
    int t = threadIdx.x;
    s[t] = (t < NUM_SCAN_BLOCKS) ? blockSums[t] : 0;
    __syncthreads();
    for (int off = 1; off < SCAN_BLK; off <<= 1) {
        int v = (t >= off) ? s[t - off] : 0;
        __syncthreads();
        s[t] += v;
        __syncthreads();
    }
    if (t < NUM_SCAN_BLOCKS) blockBase[t] = (t == 0) ? 0 : s[t - 1];
}

__global__ __launch_bounds__(SCAN_BLK) void k_block_scan(const int* __restrict__ deg,
                                                         const int* __restrict__ blockBase,
                                                         int* __restrict__ offs,
                                                         int* __restrict__ cursor, int n) {
    __shared__ int s[SCAN_BLK];
    int t = threadIdx.x;
    int i = blockIdx.x * SCAN_BLK + t;
    int cnt = (i < n) ? (deg[i] - 1) : 0;
    s[t] = cnt;
    __syncthreads();
    for (int off = 1; off < SCAN_BLK; off <<= 1) {
        int v = (t >= off) ? s[t - off] : 0;
        __syncthreads();
        s[t] += v;
        __syncthreads();
    }
    if (i < n) {
        int excl = s[t] - cnt + blockBase[blockIdx.x];
        offs[i]   = excl;
        cursor[i] = excl;
    }
}

__global__ void k_scatter(const int* __restrict__ row, const int* __restrict__ col,
                          int* __restrict__ cursor, int* __restrict__ adj, int e) {
    int i = blockIdx.x * blockDim.x + threadIdx.x;
    if (i < e) {
        int r = row[i], c = col[i];
        if (r != c) {
            int pos = atomicAdd(&cursor[r], 1);
            adj[pos] = c;
        }
    }
}

__global__ __launch_bounds__(256) void k_gather_csr(const float* __restrict__ x,
                                                    const int* __restrict__ adj,
                                                    const int* __restrict__ offs,
                                                    const int* __restrict__ deg,
                                                    float* __restrict__ out, int n) {
    int lane = threadIdx.x & 63;
    int rowi = blockIdx.x * 4 + (threadIdx.x >> 6);
    if (rowi >= n) return;

    const float2* __restrict__ x2 = (const float2*)x;
    int beg = offs[rowi];
    int cnt = deg[rowi] - 1;

    float2 acc = make_float2(0.0f, 0.0f);
    for (int base = 0; base < cnt; base += 64) {
        int m = cnt - base; if (m > 64) m = 64;
        int a = 0;
        if (lane < m) a = adj[beg + base + lane];
        for (int nb = 0; nb < m; ++nb) {
            int c = __shfl(a, nb);
            float w = rsqrtf((float)deg[c]);
            float2 v = x2[c * (DFEAT / 2) + lane];
            acc.x += w * v.x;
            acc.y += w * v.y;
        }
    }
    float di = rsqrtf((float)deg[rowi]);
    float2 self = x2[rowi * (DFEAT / 2) + lane];
    acc.x = di * (acc.x + di * self.x);
    acc.y = di * (acc.y + di * self.y);

    float nsq = acc.x * acc.x + acc.y * acc.y;
    #pragma unroll
    for (int off = 32; off > 0; off >>= 1) nsq += __shfl_xor(nsq, off);

    float un = fmaxf(sqrtf(nsq), 1e-15f);
    float th = tanhf(un);
    float scale = th / un;
    if (th > MAXNORM) scale *= MAXNORM / th;

    float2 o = make_float2(acc.x * scale, acc.y * scale);
    ((float2*)out)[rowi * (DFEAT / 2) + lane] = o;
}

// ==================== launcher ====================

extern "C" void kernel_launch(void* const* d_in, const int* in_sizes, int n_in,
                              void* d_out, int out_size, void* d_ws, size_t ws_size,
                              hipStream_t stream) {
    const float* x          = (const float*)d_in[0];
    const int*   edge_index = (const int*)d_in[1];
    const int*   row = edge_index;            // [E]
    const int*   col = edge_index + N_EDGES;  // [E]
    float* out = (float*)d_out;
    char*  ws  = (char*)d_ws;

    size_t sz_xb    = sizeof(unsigned short) * (size_t)(N_NODES + 1) * DFEAT;  // 12.80 MB
    size_t sz_adj16 = sizeof(unsigned short) * (size_t)N_NODES * CAP;          //  6.40 MB
    size_t sz_deg   = sizeof(int) * (size_t)N_NODES;
    size_t need = sz_xb + sz_adj16 + sz_deg + sizeof(int) * (1 + 2 * (size_t)OVF_CAP);

    dim3 blk(256);
    if (ws_size >= need) {
        size_t off = 0;
        unsigned int*   xb      = (unsigned int*)(ws + off);   off += sz_xb;
        unsigned short* adj16   = (unsigned short*)(ws + off); off += sz_adj16;
        int*            deg     = (int*)(ws + off);            off += sz_deg;
        int*            ovf_cnt = (int*)(ws + off);            off += sizeof(int);
        int*            ovf     = (int*)(ws + off);

        int nprep = (N_NODES + 1) * (DFEAT / 8);   // 16 threads per row incl. sentinel
        k_zero<<<dim3((N_NODES + 255) / 256), blk, 0, stream>>>(deg, ovf_cnt, N_NODES);
        k_build<<<dim3(8192), blk, 0, stream>>>(row, col, deg, adj16, ovf, ovf_cnt, N_EDGES);
        k_prep<<<dim3((nprep + 255) / 256), blk, 0, stream>>>(x, deg, xb, nprep);
        k_gather_bf<<<dim3((N_NODES + 3) / 4), blk, 0, stream>>>(xb, adj16, deg, ovf, ovf_cnt, out, N_NODES);
    } else {
        size_t off = 0;
        int* deg       = (int*)(ws + off); off += sizeof(int) * (size_t)N_NODES;
        int* offs      = (int*)(ws + off); off += sizeof(int) * (size_t)N_NODES;
        int* cursor    = (int*)(ws + off); off += sizeof(int) * (size_t)N_NODES;
        int* blockSums = (int*)(ws + off); off += sizeof(int) * (size_t)NUM_SCAN_BLOCKS;
        int* blockBase = (int*)(ws + off); off += sizeof(int) * (size_t)NUM_SCAN_BLOCKS;
        int* adj       = (int*)(ws + off);

        k_init_deg<<<dim3((N_NODES + 255) / 256), blk, 0, stream>>>(deg, N_NODES);
        k_hist<<<dim3((N_EDGES + 255) / 256), blk, 0, stream>>>(row, col, deg, N_EDGES);
        k_block_sums<<<dim3(NUM_SCAN_BLOCKS), dim3(SCAN_BLK), 0, stream>>>(deg, blockSums, N_NODES);
        k_scan_blocks<<<dim3(1), dim3(SCAN_BLK), 0, stream>>>(blockSums, blockBase);
        k_block_scan<<<dim3(NUM_SCAN_BLOCKS), dim3(SCAN_BLK), 0, stream>>>(deg, blockBase, offs, cursor, N_NODES);
        k_scatter<<<dim3((N_EDGES + 255) / 256), blk, 0, stream>>>(row, col, cursor, adj, N_EDGES);
        k_gather_csr<<<dim3((N_NODES + 3) / 4), blk, 0, stream>>>(x, adj, offs, deg, out, N_NODES);
    }
}

// Round 12
// 147.936 us; speedup vs baseline: 2.4442x; 1.0046x over previous
//
#include <hip/hip_runtime.h>
#include <math.h>

// Problem constants (match reference)
#define N_NODES 50000
#define N_EDGES 800000
#define DFEAT   128
#define MAXNORM (1.0f - 4e-3f)   // (1 - BALL_EPS)/sqrt(c), c=1
#define CAP     64               // padded adjacency slots per row (deg ~ Poisson(16), max ~45)
#define OVF_CAP 8192
#define NPART   8                // row partitions (~XCDs)
#define PSIZE   (N_NODES / NPART) // 6250 rows per partition
#define SENT    N_NODES          // sentinel node id (xb row is zeros)

// ==================== tier 1: partitioned build + pre-scaled bf16 gather ====================

__global__ void k_zero(int* __restrict__ deg, int* __restrict__ ovf_cnt, int n) {
    int i = blockIdx.x * blockDim.x + threadIdx.x;
    if (i < n) deg[i] = 0;
    if (i == 0) *ovf_cnt = 0;
}

// Row-partitioned build (r11-proven): blocks with (blockIdx&7)==p handle only
// rows in partition p; with the blockIdx%8->XCD round-robin heuristic each
// partition's deg atomics + adj stores stay in ONE XCD's L2 (no cross-XCD
// line bouncing). All partitions scan all edges (8x coalesced reads, cheap).
__global__ void k_build(const int* __restrict__ row, const int* __restrict__ col,
                        int* __restrict__ deg, unsigned short* __restrict__ adj16,
                        int* __restrict__ ovf, int* __restrict__ ovf_cnt, int e) {
    int p      = blockIdx.x & (NPART - 1);
    int vblock = blockIdx.x >> 3;
    int stride = (gridDim.x >> 3) * blockDim.x;
    int lo = p * PSIZE, hi = lo + PSIZE;
    for (int i = vblock * blockDim.x + threadIdx.x; i < e; i += stride) {
        int r = row[i], c = col[i];
        if (r < lo || r >= hi || r == c) continue;
        int pos = atomicAdd(&deg[r], 1);
        if (pos < CAP) adj16[r * CAP + pos] = (unsigned short)c;
        else {
            int o = atomicAdd(ovf_cnt, 1);
            if (o < OVF_CAP) { ovf[2 * o] = r; ovf[2 * o + 1] = c; }
        }
    }
}

// After build: xb[node] = bf16(x[node] * rsqrt(deg[node]+1)); row N_NODES = zeros.
// 16 threads per row (8 floats each).
__global__ __launch_bounds__(256) void k_prep(const float* __restrict__ x,
                                              const int* __restrict__ deg,
                                              unsigned int* __restrict__ xb,   // packed 2x bf16 per word
                                              int nthreads) {
    int t = blockIdx.x * blockDim.x + threadIdx.x;
    if (t >= nthreads) return;

    int node = t >> 4;            // 16 threads per row
    int part = t & 15;            // which 8-float chunk
    unsigned int w[4];
    if (node < N_NODES) {
        float dis = rsqrtf((float)(deg[node] + 1));
        const float4* x4 = (const float4*)(x + (size_t)node * DFEAT + part * 8);
        float4 a = x4[0];
        float4 b = x4[1];
        float fs[8] = {a.x, a.y, a.z, a.w, b.x, b.y, b.z, b.w};
        #pragma unroll
        for (int k = 0; k < 4; ++k) {
            unsigned int lo = __float_as_uint(fs[2 * k] * dis);
            unsigned int hi = __float_as_uint(fs[2 * k + 1] * dis);
            lo = (lo + 0x7FFFu + ((lo >> 16) & 1u)) >> 16;          // RNE to bf16
            hi = (hi + 0x7FFFu + ((hi >> 16) & 1u)) >> 16;
            w[k] = lo | (hi << 16);
        }
    } else {
        w[0] = w[1] = w[2] = w[3] = 0u;   // sentinel row: zeros
    }
    ((uint4*)xb)[t] = make_uint4(w[0], w[1], w[2], w[3]);
}

__device__ __forceinline__ float bf_lo(unsigned int w) { return __uint_as_float(w << 16); }
__device__ __forceinline__ float bf_hi(unsigned int w) { return __uint_as_float(w & 0xFFFF0000u); }

// One wave per destination row. STRAIGHT-LINE K-body: all neighbor indices are
// in register `a` right after the adj load, so neighbors 0-31 are processed as
// 16 fully-independent uint2 loads (compiler batch-issues them -> ONE latency
// wait instead of 4 serial rounds). deg>32 tail (P~2e-4) is a wave-uniform
// rare branch. Sentinel-masked lanes hit the zero row (L1-resident).
__global__ __launch_bounds__(256) void k_gather_bf(const unsigned int* __restrict__ xb,
                                                   const unsigned short* __restrict__ adj16,
                                                   const int* __restrict__ deg,
                                                   const int* __restrict__ ovf,
                                                   const int* __restrict__ ovf_cnt,
                                                   float* __restrict__ out, int n) {
    int lane = threadIdx.x & 63;
    int half = lane >> 5;
    int fl   = lane & 31;
    int rowi = blockIdx.x * 4 + (threadIdx.x >> 6);
    if (rowi >= n) return;

    int cnt    = deg[rowi];
    int capcnt = cnt < CAP ? cnt : CAP;

    int a = SENT;
    if (lane < capcnt) a = (int)adj16[rowi * CAP + lane];  // coalesced 128B per row

    const unsigned int* __restrict__ xw = xb + 2 * fl;     // lane's word pair base

    float acc0 = 0.f, acc1 = 0.f, acc2 = 0.f, acc3 = 0.f;

    // neighbors 0..31: 16 independent loads, one batch
    {
        int c[16];
        #pragma unroll
        for (int j = 0; j < 16; ++j) c[j] = __shfl(a, 2 * j + half);
        uint2 v[16];
        #pragma unroll
        for (int j = 0; j < 16; ++j) v[j] = *(const uint2*)(xw + c[j] * (DFEAT / 2));
        #pragma unroll
        for (int j = 0; j < 16; ++j) {
            acc0 += bf_lo(v[j].x); acc1 += bf_hi(v[j].x);
            acc2 += bf_lo(v[j].y); acc3 += bf_hi(v[j].y);
        }
    }
    // neighbors 32..63: rare (deg>32), wave-uniform branch
    if (capcnt > 32) {
        int c[16];
        #pragma unroll
        for (int j = 0; j < 16; ++j) c[j] = __shfl(a, 32 + 2 * j + half);
        uint2 v[16];
        #pragma unroll
        for (int j = 0; j < 16; ++j) v[j] = *(const uint2*)(xw + c[j] * (DFEAT / 2));
        #pragma unroll
        for (int j = 0; j < 16; ++j) {
            acc0 += bf_lo(v[j].x); acc1 += bf_hi(v[j].x);
            acc2 += bf_lo(v[j].y); acc3 += bf_hi(v[j].y);
        }
    }

    // overflow edges (statistically never non-empty); lanes 0-31 only, pre-combine
    int novf = *ovf_cnt;
    if (novf > 0 && half == 0) {
        for (int k = 0; k < novf; ++k) {
            if (ovf[2 * k] == rowi) {
                uint2 v = *(const uint2*)(xw + ovf[2 * k + 1] * (DFEAT / 2));
                acc0 += bf_lo(v.x); acc1 += bf_hi(v.x);
                acc2 += bf_lo(v.y); acc3 += bf_hi(v.y);
            }
        }
    }

    // combine halves (afterwards both halves hold identical full sums)
    acc0 += __shfl_xor(acc0, 32);
    acc1 += __shfl_xor(acc1, 32);
    acc2 += __shfl_xor(acc2, 32);
    acc3 += __shfl_xor(acc3, 32);

    // self term: xb[rowi] pre-scaled by dis[rowi]
    uint2 sv = *(const uint2*)(xw + rowi * (DFEAT / 2));
    acc0 += bf_lo(sv.x); acc1 += bf_hi(sv.x);
    acc2 += bf_lo(sv.y); acc3 += bf_hi(sv.y);

    float di = rsqrtf((float)(cnt + 1));             // dis[row]
    acc0 *= di; acc1 *= di; acc2 *= di; acc3 *= di;

    // norm^2: reduce within each 32-half (halves identical)
    float nsq = acc0 * acc0 + acc1 * acc1 + acc2 * acc2 + acc3 * acc3;
    #pragma unroll
    for (int off = 16; off > 0; off >>= 1) nsq += __shfl_xor(nsq, off);

    float un = fmaxf(sqrtf(nsq), 1e-15f);
    float th = tanhf(un);
    float scale = th / un;                           // expmap0
    if (th > MAXNORM) scale *= MAXNORM / th;         // proj clamp (||p|| == tanh(un))

    if (half == 0) {
        float4 o = make_float4(acc0 * scale, acc1 * scale, acc2 * scale, acc3 * scale);
        *(float4*)(out + (size_t)rowi * DFEAT + 4 * fl) = o;
    }
}

// ==================== fallback: CSR path (proven round-2) ====================

#define SCAN_BLK 256
#define NUM_SCAN_BLOCKS ((N_NODES + SCAN_BLK - 1) / SCAN_BLK)

__global__ void k_init_deg(int* __restrict__ deg, int n) {
    int i = blockIdx.x * blockDim.x + threadIdx.x;
    if (i < n) deg[i] = 1;
}

__global__ void k_hist(const int* __restrict__ row, const int* __restrict__ col,
                       int* __restrict__ deg, int e) {
    int i = blockIdx.x * blockDim.x + threadIdx.x;
    if (i < e) {
        int r = row[i], c = col[i];
        if (r != c) atomicAdd(&deg[r], 1);
    }
}

__global__ __launch_bounds__(SCAN_BLK) void k_block_sums(const int* __restrict__ deg,
                                                         int* __restrict__ blockSums, int n) {
    __shared__ int s[SCAN_BLK];
    int t = threadIdx.x;
    int i = blockIdx.x * SCAN_BLK + t;
    s[t] = (i < n) ? (deg[i] - 1) : 0;
    __syncthreads();
    for (int off = SCAN_BLK / 2; off > 0; off >>= 1) {
        if (t < off) s[t] += s[t + off];
        __syncthreads();
    }
    if (t == 0) blockSums[blockIdx.x] = s[0];
}

__global__ __launch_bounds__(SCAN_BLK) void k_scan_blocks(const int* __restrict__ blockSums,
                                                          int* __restrict__ blockBase) {
    __shared__ int s[SCAN_BLK];
    int t = threadIdx.x;
    s[t] = (t < NUM_SCAN_BLOCKS) ? blockSums[t] : 0;
    __syncthreads();
    for (int off = 1; off < SCAN_BLK; off <<= 1) {
        int v = (t >= off) ? s[t - off] : 0;
        __syncthreads();
        s[t] += v;
        __syncthreads();
    }
    if (t < NUM_SCAN_BLOCKS) blockBase[t] = (t == 0) ? 0 : s[t - 1];
}

__global__ __launch_bounds__(SCAN_BLK) void k_block_scan(const int* __restrict__ deg,
                                                         const int* __restrict__ blockBase,
                                                         int* __restrict__ offs,
                                                         int* __restrict__ cursor, int n) {
    __shared__ int s[SCAN_BLK];
    int t = threadIdx.x;
    int i = blockIdx.x * SCAN_BLK + t;
    int cnt = (i < n) ? (deg[i] - 1) : 0;
    s[t] = cnt;
    __syncthreads();
    for (int off = 1; off < SCAN_BLK; off <<= 1) {
        int v = (t >= off) ? s[t - off] : 0;
        __syncthreads();
        s[t] += v;
        __syncthreads();
    }
    if (i < n) {
        int excl = s[t] - cnt + blockBase[blockIdx.x];
        offs[i]   = excl;
        cursor[i] = excl;
    }
}

__global__ void k_scatter(const int* __restrict__ row, const int* __restrict__ col,
                          int* __restrict__ cursor, int* __restrict__ adj, int e) {
    int i = blockIdx.x * blockDim.x + threadIdx.x;
    if (i < e) {
        int r = row[i], c = col[i];
        if (r != c) {
            int pos = atomicAdd(&cursor[r], 1);
            adj[pos] = c;
        }
    }
}

__global__ __launch_bounds__(256) void k_gather_csr(const float* __restrict__ x,
                                                    const int* __restrict__ adj,
                                                    const int* __restrict__ offs,
                                                    const int* __restrict__ deg,
                                                    float* __restrict__ out, int n) {
    int lane = threadIdx.x & 63;
    int rowi = blockIdx.x * 4 + (threadIdx.x >> 6);
    if (rowi >= n) return;

    const float2* __restrict__ x2 = (const float2*)x;
    int beg = offs[rowi];
    int cnt = deg[rowi] - 1;

    float2 acc = make_float2(0.0f, 0.0f);
    for (int base = 0; base < cnt; base += 64) {
        int m = cnt - base; if (m > 64) m = 64;
        int a = 0;
        if (lane < m) a = adj[beg + base + lane];
        for (int nb = 0; nb < m; ++nb) {
            int c = __shfl(a, nb);
            float w = rsqrtf((float)deg[c]);
            float2 v = x2[c * (DFEAT / 2) + lane];
            acc.x += w * v.x;
            acc.y += w * v.y;
        }
    }
    float di = rsqrtf((float)deg[rowi]);
    float2 self = x2[rowi * (DFEAT / 2) + lane];
    acc.x = di * (acc.x + di * self.x);
    acc.y = di * (acc.y + di * self.y);

    float nsq = acc.x * acc.x + acc.y * acc.y;
    #pragma unroll
    for (int off = 32; off > 0; off >>= 1) nsq += __shfl_xor(nsq, off);

    float un = fmaxf(sqrtf(nsq), 1e-15f);
    float th = tanhf(un);
    float scale = th / un;
    if (th > MAXNORM) scale *= MAXNORM / th;

    float2 o = make_float2(acc.x * scale, acc.y * scale);
    ((float2*)out)[rowi * (DFEAT / 2) + lane] = o;
}

// ==================== launcher ====================

extern "C" void kernel_launch(void* const* d_in, const int* in_sizes, int n_in,
                              void* d_out, int out_size, void* d_ws, size_t ws_size,
                              hipStream_t stream) {
    const float* x          = (const float*)d_in[0];
    const int*   edge_index = (const int*)d_in[1];
    const int*   row = edge_index;            // [E]
    const int*   col = edge_index + N_EDGES;  // [E]
    float* out = (float*)d_out;
    char*  ws  = (char*)d_ws;

    size_t sz_xb    = sizeof(unsigned short) * (size_t)(N_NODES + 1) * DFEAT;  // 12.80 MB
    size_t sz_adj16 = sizeof(unsigned short) * (size_t)N_NODES * CAP;          //  6.40 MB
    size_t sz_deg   = sizeof(int) * (size_t)N_NODES;
    size_t need = sz_xb + sz_adj16 + sz_deg + sizeof(int) * (1 + 2 * (size_t)OVF_CAP);

    dim3 blk(256);
    if (ws_size >= need) {
        size_t off = 0;
        unsigned int*   xb      = (unsigned int*)(ws + off);   off += sz_xb;
        unsigned short* adj16   = (unsigned short*)(ws + off); off += sz_adj16;
        int*            deg     = (int*)(ws + off);            off += sz_deg;
        int*            ovf_cnt = (int*)(ws + off);            off += sizeof(int);
        int*            ovf     = (int*)(ws + off);

        int nprep = (N_NODES + 1) * (DFEAT / 8);   // 16 threads per row incl. sentinel
        k_zero<<<dim3((N_NODES + 255) / 256), blk, 0, stream>>>(deg, ovf_cnt, N_NODES);
        k_build<<<dim3(8192), blk, 0, stream>>>(row, col, deg, adj16, ovf, ovf_cnt, N_EDGES);
        k_prep<<<dim3((nprep + 255) / 256), blk, 0, stream>>>(x, deg, xb, nprep);
        k_gather_bf<<<dim3((N_NODES + 3) / 4), blk, 0, stream>>>(xb, adj16, deg, ovf, ovf_cnt, out, N_NODES);
    } else {
        size_t off = 0;
        int* deg       = (int*)(ws + off); off += sizeof(int) * (size_t)N_NODES;
        int* offs      = (int*)(ws + off); off += sizeof(int) * (size_t)N_NODES;
        int* cursor    = (int*)(ws + off); off += sizeof(int) * (size_t)N_NODES;
        int* blockSums = (int*)(ws + off); off += sizeof(int) * (size_t)NUM_SCAN_BLOCKS;
        int* blockBase = (int*)(ws + off); off += sizeof(int) * (size_t)NUM_SCAN_BLOCKS;
        int* adj       = (int*)(ws + off);

        k_init_deg<<<dim3((N_NODES + 255) / 256), blk, 0, stream>>>(deg, N_NODES);
        k_hist<<<dim3((N_EDGES + 255) / 256), blk, 0, stream>>>(row, col, deg, N_EDGES);
        k_block_sums<<<dim3(NUM_SCAN_BLOCKS), dim3(SCAN_BLK), 0, stream>>>(deg, blockSums, N_NODES);
        k_scan_blocks<<<dim3(1), dim3(SCAN_BLK), 0, stream>>>(blockSums, blockBase);
        k_block_scan<<<dim3(NUM_SCAN_BLOCKS), dim3(SCAN_BLK), 0, stream>>>(deg, blockBase, offs, cursor, N_NODES);
        k_scatter<<<dim3((N_EDGES + 255) / 256), blk, 0, stream>>>(row, col, cursor, adj, N_EDGES);
        k_gather_csr<<<dim3((N_NODES + 3) / 4), blk, 0, stream>>>(x, adj, offs, deg, out, N_NODES);
    }
}